// Round 2
// baseline (302.500 us; speedup 1.0000x reference)
//
#include <hip/hip_runtime.h>

// DCNv1 forward, fp32 direct kernel.
// Shapes (fixed by the reference): x[8,64,128,128], offset[8,18,128,128],
// weight[64,64,3,3], bias[64] -> out[8,64,128,128].

constexpr int Bn  = 8;
constexpr int Cn  = 64;
constexpr int Hn  = 128;
constexpr int Wn  = 128;
constexpr int OCn = 64;
constexpr int Kn  = 9;          // 3x3
constexpr int HWn = Hn * Wn;    // 16384
constexpr int CK  = Cn * Kn;    // 576

// Tiny transpose: w[oc][c][k] -> wT[k][c][oc] so the main kernel's
// wave-uniform weight reads are contiguous (s_load_dwordx16-friendly).
__global__ __launch_bounds__(256) void wtrans_kernel(const float* __restrict__ w,
                                                     float* __restrict__ wT) {
  int t = blockIdx.x * 256 + threadIdx.x;  // t = (k*Cn + c)*OCn + oc
  if (t >= Kn * Cn * OCn) return;
  int oc = t & (OCn - 1);
  int kc = t >> 6;
  int c  = kc % Cn;
  int k  = kc / Cn;
  wT[t] = w[oc * CK + c * Kn + k];
}

template <bool TR>
__global__ __launch_bounds__(256) void dcn_kernel(
    const float* __restrict__ x, const float* __restrict__ off,
    const float* __restrict__ wgt,  // TR ? wT[k][c][oc] : w[oc][c][k]
    const float* __restrict__ bias,
    float* __restrict__ out) {
  const int pix = blockIdx.x * 256 + threadIdx.x;
  const int b   = pix >> 14;         // / 16384
  const int hw  = pix & (HWn - 1);
  const int ho  = hw >> 7;
  const int wo  = hw & (Wn - 1);

  float acc[OCn];
#pragma unroll
  for (int oc = 0; oc < OCn; ++oc) acc[oc] = bias[oc];  // uniform scalar loads

  const float* xb  = x + b * (Cn * HWn);
  const float* ofb = off + b * (2 * Kn * HWn) + hw;

  for (int k = 0; k < Kn; ++k) {
    // offset channels: 2k -> dy, 2k+1 -> dx (k-major, then y/x)
    const float oy = ofb[(2 * k + 0) * HWn];
    const float ox = ofb[(2 * k + 1) * HWn];
    const float py = oy + (float)(ho - 1 + k / 3);  // base_y = ho*1 - 1, ky = k/3
    const float px = ox + (float)(wo - 1 + k % 3);

    const float y0f = floorf(py), x0f = floorf(px);
    const float ly = py - y0f, lx = px - x0f;
    const int y0 = (int)y0f, x0 = (int)x0f;
    const int y1 = y0 + 1,  x1 = x0 + 1;

    const bool vy0 = (unsigned)y0 < (unsigned)Hn;
    const bool vy1 = (unsigned)y1 < (unsigned)Hn;
    const bool vx0 = (unsigned)x0 < (unsigned)Wn;
    const bool vx1 = (unsigned)x1 < (unsigned)Wn;

    const int y0c = min(max(y0, 0), Hn - 1), y1c = min(max(y1, 0), Hn - 1);
    const int x0c = min(max(x0, 0), Wn - 1), x1c = min(max(x1, 0), Wn - 1);

    const float w00 = (vy0 && vx0) ? (1.f - ly) * (1.f - lx) : 0.f;
    const float w01 = (vy0 && vx1) ? (1.f - ly) * lx         : 0.f;
    const float w10 = (vy1 && vx0) ? ly * (1.f - lx)         : 0.f;
    const float w11 = (vy1 && vx1) ? ly * lx                 : 0.f;

    const int i00 = y0c * Wn + x0c, i01 = y0c * Wn + x1c;
    const int i10 = y1c * Wn + x0c, i11 = y1c * Wn + x1c;

#pragma unroll 2
    for (int c = 0; c < Cn; ++c) {
      const float* xc = xb + c * HWn;
      const float v = fmaf(w00, xc[i00],
                      fmaf(w01, xc[i01],
                      fmaf(w10, xc[i10], w11 * xc[i11])));
      const float* wrow = TR ? (wgt + (k * Cn + c) * OCn) : (wgt + c * Kn + k);
#pragma unroll
      for (int oc = 0; oc < OCn; ++oc) {
        const float wv = TR ? wrow[oc] : wrow[oc * CK];
        acc[oc] = fmaf(v, wv, acc[oc]);
      }
    }
  }

  float* ob = out + b * (OCn * HWn) + hw;
#pragma unroll
  for (int oc = 0; oc < OCn; ++oc) ob[oc * HWn] = acc[oc];  // coalesced per oc
}

extern "C" void kernel_launch(void* const* d_in, const int* in_sizes, int n_in,
                              void* d_out, int out_size, void* d_ws, size_t ws_size,
                              hipStream_t stream) {
  const float* x    = (const float*)d_in[0];
  const float* off  = (const float*)d_in[1];
  const float* wgt  = (const float*)d_in[2];
  const float* bias = (const float*)d_in[3];
  float* out        = (float*)d_out;

  const size_t wT_bytes = (size_t)Kn * Cn * OCn * sizeof(float);  // 147456 B
  const int npix_blocks = (Bn * HWn) / 256;                       // 512

  if (ws_size >= wT_bytes) {
    float* wT = (float*)d_ws;
    wtrans_kernel<<<(Kn * Cn * OCn + 255) / 256, 256, 0, stream>>>(wgt, wT);
    dcn_kernel<true><<<npix_blocks, 256, 0, stream>>>(x, off, wT, bias, out);
  } else {
    dcn_kernel<false><<<npix_blocks, 256, 0, stream>>>(x, off, wgt, bias, out);
  }
}